// Round 6
// baseline (80.211 us; speedup 1.0000x reference)
//
#include <hip/hip_runtime.h>
#include <math.h>

// KDE, dot-product form: sqd = ||x||^2 + ||t||^2 - 2 x.t
// exp(-sqd/(2*var)) = exp2(EXP2_SCALE*sqd), var=0.04^2, 2var=0.0032
//
// R5 (re-run; previous bench was an infra failure): main stages each 16-row
// train chunk (4 KB) + norms in LDS (coalesced), inner loop reads rows via
// uniform-address ds_read_b128 broadcast -> no per-row global/scalar-load
// latency. Test vectors stay per-lane in VGPRs, loaded once from a transposed
// copy built by a proper LDS transpose in prep.
//
// ws layout (floats): [0,1024)    EXP2_SCALE*||test_i||^2
//                     [1024,5120) EXP2_SCALE*||train_j||^2
//                     [8192,+64K) testT[k][i] = test[i][k]  (256 KB)

#define D          64
#define N_TRAIN    4096
#define N_TEST     1024
#define TT_OFF     8192
#define ROWS       16                       // train rows per chunk
#define CHUNKS     (N_TRAIN / ROWS)         // 256
#define EXP2_SCALE (-450.84220027780106f)   // -log2(e)/0.0032
#define NEG2SCALE  (901.6844005556021f)     // -2*EXP2_SCALE
#define COEF       (9.973557010035818f)     // 1/sqrt(2*pi*var)
#define MEAN_SCALE (COEF / 4096.0f)

__global__ __launch_bounds__(256) void kde_prep(
    const float* __restrict__ test,
    const float* __restrict__ train,
    float* __restrict__ out,
    float* __restrict__ ws)
{
    __shared__ float tile[64][65];
    const int t = threadIdx.x;
    const int b = blockIdx.x;

    // Blocks 0..15: transpose a 64x64 tile of test via LDS (both sides coalesced).
    if (b < 16) {
        const int r0 = b * 64;
        #pragma unroll
        for (int i = 0; i < 4; ++i) {
            const int f   = t + i * 256;     // float4 unit 0..1023
            const int row = f >> 4;
            const int c4  = f & 15;
            float4 v = ((const float4*)(test + (size_t)(r0 + row) * D))[c4];
            tile[row][c4 * 4 + 0] = v.x;
            tile[row][c4 * 4 + 1] = v.y;
            tile[row][c4 * 4 + 2] = v.z;
            tile[row][c4 * 4 + 3] = v.w;
        }
        __syncthreads();
        #pragma unroll
        for (int i = 0; i < 4; ++i) {
            const int g  = t + i * 256;      // float4 unit 0..1023
            const int k  = g >> 4;
            const int rg = g & 15;
            float4 v;
            v.x = tile[rg * 4 + 0][k];
            v.y = tile[rg * 4 + 1][k];
            v.z = tile[rg * 4 + 2][k];
            v.w = tile[rg * 4 + 3][k];
            ((float4*)(ws + TT_OFF + (size_t)k * 1024 + r0))[rg] = v;
        }
    }

    // All 20 blocks: zero out + scaled squared norms (test rows then train).
    const int j = b * 256 + t;               // 0..5119
    if (j < N_TEST) out[j] = 0.0f;
    if (j < N_TEST + N_TRAIN) {
        const float* src = (j < N_TEST) ? (test + (size_t)j * D)
                                        : (train + (size_t)(j - N_TEST) * D);
        const float4* p = (const float4*)src;
        float n0 = 0.f, n1 = 0.f, n2 = 0.f, n3 = 0.f;
        #pragma unroll
        for (int c = 0; c < D / 4; ++c) {
            float4 v = p[c];
            n0 = fmaf(v.x, v.x, n0); n1 = fmaf(v.y, v.y, n1);
            n2 = fmaf(v.z, v.z, n2); n3 = fmaf(v.w, v.w, n3);
        }
        ws[j] = ((n0 + n1) + (n2 + n3)) * EXP2_SCALE;
    }
}

__global__ __launch_bounds__(256) void kde_main(
    const float* __restrict__ train,
    const float* __restrict__ ws,
    float* __restrict__ out)
{
    __shared__ float4 srow[ROWS][16];        // chunk rows, float4 units
    __shared__ float  snorm[ROWS];           // scaled ||t||^2 per row

    const int t     = threadIdx.x;
    const int lane  = t & 63;
    const int wv    = t >> 6;
    const int tg    = blockIdx.x & 3;        // test group (256 tests)
    const int chunk = blockIdx.x >> 2;       // train chunk (16 rows)
    const int ti    = tg * 256 + wv * 64 + lane;
    const int j0    = chunk * ROWS;

    // Cooperative stage: 16 rows x 64 floats = 256 float4, one per thread.
    srow[t >> 4][t & 15] = ((const float4*)(train + (size_t)j0 * D))[t];
    if (t < ROWS) snorm[t] = ws[N_TEST + j0 + t];

    // Per-lane test vector from transposed copy (coalesced, once).
    const float* __restrict__ tt = ws + TT_OFF + ti;
    float x[D];
    #pragma unroll
    for (int k = 0; k < D; ++k) x[k] = tt[(size_t)k * 1024];
    const float xn = ws[ti];

    __syncthreads();

    float sum = 0.0f;
    #pragma unroll 4
    for (int jj = 0; jj < ROWS; ++jj) {
        float d0 = 0.f, d1 = 0.f, d2 = 0.f, d3 = 0.f;
        #pragma unroll
        for (int c = 0; c < 16; ++c) {
            float4 tv = srow[jj][c];         // uniform addr -> LDS broadcast
            d0 = fmaf(tv.x, x[4 * c + 0], d0);
            d1 = fmaf(tv.y, x[4 * c + 1], d1);
            d2 = fmaf(tv.z, x[4 * c + 2], d2);
            d3 = fmaf(tv.w, x[4 * c + 3], d3);
        }
        const float dot = (d0 + d1) + (d2 + d3);
        sum += exp2f(fmaf(dot, NEG2SCALE, xn + snorm[jj]));
    }

    atomicAdd(&out[ti], sum * MEAN_SCALE);   // coalesced, per-lane
}

extern "C" void kernel_launch(void* const* d_in, const int* in_sizes, int n_in,
                              void* d_out, int out_size, void* d_ws, size_t ws_size,
                              hipStream_t stream) {
    const float* test  = (const float*)d_in[0];   // [4,256,64]
    const float* train = (const float*)d_in[1];   // [4096,64]
    float* out = (float*)d_out;                   // 1024 floats
    float* ws  = (float*)d_ws;

    kde_prep<<<dim3(20), dim3(256), 0, stream>>>(test, train, out, ws);
    kde_main<<<dim3(4 * CHUNKS), dim3(256), 0, stream>>>(train, ws, out);
}